// Round 4
// baseline (3681.991 us; speedup 1.0000x reference)
//
#include <hip/hip_runtime.h>

// ===========================================================================
// Compile-time construction of the e3nn real Wigner-3j path tensor.
// (numerically validated in round 3: absmax 0.031 vs threshold 0.259)
// ===========================================================================
namespace cg {

constexpr double csqrt(double x) {
    double g = x < 1.0 ? 1.0 : x;
    for (int i = 0; i < 64; ++i) g = 0.5 * (g + x / g);
    return g;
}
constexpr double fact(int n) { double r = 1.0; for (int i = 2; i <= n; ++i) r *= (double)i; return r; }

constexpr double su2cg(int j1, int j2, int j3, int m1, int m2, int m3) {
    if (m1 + m2 != m3) return 0.0;
    double pre = csqrt((2.0*j3+1.0)*fact(j3+j1-j2)*fact(j3-j1+j2)*fact(j1+j2-j3)
                       *fact(j3+m3)*fact(j3-m3)
                       /(fact(j1+j2+j3+1)*fact(j1-m1)*fact(j1+m1)*fact(j2-m2)*fact(j2+m2)));
    double S = 0.0;
    for (int v = 0; v <= j1 + j2 + j3; ++v) {
        int b1 = j3-j1+j2-v, b2 = j3+m3-v, b3 = v+j1-j2-m3, b4 = j2+j3+m1-v, b5 = j1-m1+v;
        if (b1 < 0 || b2 < 0 || b3 < 0 || b4 < 0 || b5 < 0) continue;
        double term = fact(b4)*fact(b5)/(fact(v)*fact(b1)*fact(b2)*fact(b3));
        S += ((v + j2 + m2) & 1) ? -term : term;
    }
    return pre * S;
}

struct CD { double re, im; };
constexpr CD cmul(CD a, CD b) { return { a.re*b.re - a.im*b.im, a.re*b.im + a.im*b.re }; }

constexpr CD qent(int l, int r, int c) {
    const double s = 0.70710678118654752440;
    CD v{0.0, 0.0};
    int m = r - l;
    if (m < 0)       { if (c == l - m) v = { s, 0.0 }; else if (c == l + m) v = { 0.0, -s }; }
    else if (m == 0) { if (c == l)     v = { 1.0, 0.0 }; }
    else             { double sg = (m & 1) ? -1.0 : 1.0;
                       if (c == l + m) v = { sg*s, 0.0 }; else if (c == l - m) v = { 0.0, sg*s }; }
    if      (l == 1) v = { v.im, -v.re };
    else if (l == 2) v = { -v.re, -v.im };
    return v;
}

constexpr int PA_[11] = {0,0,0,1,1,1,1,2,2,2,2};
constexpr int PB_[11] = {0,1,2,0,1,1,2,0,1,2,2};
constexpr int PC_[11] = {0,1,2,1,0,2,1,2,1,0,2};
constexpr double FAN_[3] = {3.0, 4.0, 4.0};

struct KTab { float v[9][9][9]; };

constexpr KTab buildK() {
    KTab T{};
    for (int p = 0; p < 11; ++p) {
        const int a = PA_[p], b = PB_[p], c = PC_[p];
        double cgt[5][5] = {};
        for (int i = 0; i < 2*a+1; ++i)
            for (int k = 0; k < 2*b+1; ++k) {
                int m3 = (i-a) + (k-b);
                cgt[i][k] = (m3 >= -c && m3 <= c) ? su2cg(a,b,c,i-a,k-b,m3) : 0.0;
            }
        double R[5][5][5] = {};
        double nrm = 0.0;
        for (int j = 0; j < 2*a+1; ++j)
            for (int l = 0; l < 2*b+1; ++l)
                for (int m = 0; m < 2*c+1; ++m) {
                    double re = 0.0;
                    for (int i = 0; i < 2*a+1; ++i)
                        for (int k = 0; k < 2*b+1; ++k) {
                            double g = cgt[i][k];
                            if (g == 0.0) continue;
                            int n = (i-a) + (k-b) + c;
                            CD t12 = cmul(qent(a,i,j), qent(b,k,l));
                            CD q3  = qent(c,n,m);
                            re += (t12.re*q3.re + t12.im*q3.im) * g;
                        }
                    R[j][l][m] = re;
                    nrm += re*re;
                }
        double sc = csqrt((2.0*c+1.0)/FAN_[c]) / csqrt(nrm);
        for (int j = 0; j < 2*a+1; ++j)
            for (int l = 0; l < 2*b+1; ++l)
                for (int m = 0; m < 2*c+1; ++m)
                    T.v[a*a+j][b*b+l][c*c+m] = (float)(R[j][l][m] * sc);
    }
    return T;
}

constexpr KTab KT = buildK();

constexpr int pathOf(int a, int b, int c) {
    for (int p = 0; p < 11; ++p) if (PA_[p]==a && PB_[p]==b && PC_[p]==c) return p;
    return 0;
}
constexpr bool allowedC(int a, int b, int c) {
    int lo = a > b ? a - b : b - a;
    return c >= lo && c <= a + b && (((a + b + c) & 1) == 0);
}
constexpr bool anyNZ(int i, int j) {
    for (int k = 0; k < 9; ++k) if (KT.v[i][j][k] != 0.0f) return true;
    return false;
}
constexpr bool rowNZ(int a, int b, int c, int dk) {
    for (int di = 0; di < 2*a+1; ++di)
        for (int dj = 0; dj < 2*b+1; ++dj)
            if (KT.v[a*a+di][b*b+dj][c*c+dk] != 0.0f) return true;
    return false;
}

} // namespace cg

// ===========================================================================
// Main kernel: ONE WAVE per block (64 threads), 2 items/thread, 128 items.
// global_load_lds stage-in (coalesced, no VGPR round trip), wave-local
// "barriers" (no lockstep across waves), LDS-staged coalesced store.
// LDS ~10 KB, small register state -> many independent waves per CU.
// ===========================================================================

#define BLK   64
#define TPV   2
#define IPB   (BLK * TPV)      // 128 items per block
#define TILEF (IPB * 9)        // 1152 floats per tile
#define TILE4 (TILEF / 4)      // 288 float4

#define GL_LDS16(g, l) __builtin_amdgcn_global_load_lds( \
    (__attribute__((address_space(1))) void*)(g), \
    (__attribute__((address_space(3))) void*)(l), 16, 0, 0)
#define GL_LDS4(g, l) __builtin_amdgcn_global_load_lds( \
    (__attribute__((address_space(1))) void*)(g), \
    (__attribute__((address_space(3))) void*)(l), 4, 0, 0)

__global__ __launch_bounds__(BLK) void tp_main_kernel(
        const float* __restrict__ x, const float* __restrict__ y,
        float* __restrict__ out, const float* __restrict__ tpw,
        const float* __restrict__ Wfx, const float* __restrict__ bfx,
        const float* __restrict__ Wfy, const float* __restrict__ bfy)
{
    __shared__ __align__(16) float tx[TILEF];
    __shared__ __align__(16) float ty[TILEF];
    __shared__ __align__(16) float Wc[9][24];   // [k][0..8]=Wfx row, [k][12..20]=Wfy row
    __shared__ float bs[9];

    const int  lane = threadIdx.x;
    const long blk  = blockIdx.x;

    // ---- stage tiles via async global->LDS (coalesced 1KiB per instr) ----
    const float* xb = x + blk * (long)TILEF;
    const float* yb = y + blk * (long)TILEF;
    #pragma unroll
    for (int r = 0; r < 4; ++r) {
        GL_LDS16(xb + r * 256 + lane * 4, &tx[r * 256]);
        GL_LDS16(yb + r * 256 + lane * 4, &ty[r * 256]);
    }
    #pragma unroll
    for (int c2 = 0; c2 < 2; ++c2) {
        GL_LDS4(xb + 1024 + c2 * 64 + lane, &tx[1024 + c2 * 64]);
        GL_LDS4(yb + 1024 + c2 * 64 + lane, &ty[1024 + c2 * 64]);
    }

    // ---- stage weights (regular loads, overlap with the DMA above) ----
    #pragma unroll
    for (int u0 = 0; u0 < 2; ++u0) {
        int u = u0 * BLK + lane;
        if (u < 81) { Wc[u / 9][u % 9] = Wfx[u]; Wc[u / 9][12 + u % 9] = Wfy[u]; }
    }
    if (lane < 9) bs[lane] = bfx[lane] + bfy[lane];

    float w[11];
    #pragma unroll
    for (int p = 0; p < 11; ++p) {
        union { float f; int i; } u;
        u.f = tpw[p];
        u.i = __builtin_amdgcn_readfirstlane(u.i);
        w[p] = u.f;
    }

    __syncthreads();   // single wave: drains vmcnt/lgkmcnt, no cross-wave lockstep

    // ---- per-thread compute: 2 consecutive items ----
    const int base = lane * 18;
    float xl[18], yl[18], acc[18];   // [v*9 + comp]
    #pragma unroll
    for (int i = 0; i < 18; ++i) { xl[i] = tx[base + i]; yl[i] = ty[base + i]; }

    #pragma unroll
    for (int k = 0; k < 9; ++k) { float bb = bs[k]; acc[k] = bb; acc[9 + k] = bb; }

    // linear branches
    #pragma unroll
    for (int k = 0; k < 9; ++k) {
        float4 wxa = *reinterpret_cast<const float4*>(&Wc[k][0]);
        float4 wxb = *reinterpret_cast<const float4*>(&Wc[k][4]);
        float  wx8 = Wc[k][8];
        float4 wya = *reinterpret_cast<const float4*>(&Wc[k][12]);
        float4 wyb = *reinterpret_cast<const float4*>(&Wc[k][16]);
        float  wy8 = Wc[k][20];
        const float wxr[9] = {wxa.x,wxa.y,wxa.z,wxa.w,wxb.x,wxb.y,wxb.z,wxb.w,wx8};
        const float wyr[9] = {wya.x,wya.y,wya.z,wya.w,wyb.x,wyb.y,wyb.z,wyb.w,wy8};
        float s0 = acc[k], s1 = acc[9 + k];
        #pragma unroll
        for (int i = 0; i < 9; ++i) {
            s0 += wxr[i] * xl[i]     + wyr[i] * yl[i];
            s1 += wxr[i] * xl[9 + i] + wyr[i] * yl[9 + i];
        }
        acc[k] = s0; acc[9 + k] = s1;
    }

    // tensor product: compile-time-folded sparse 3j constants.
    // Path accumulators: only entries with rowNZ are ever touched.
    #pragma unroll
    for (int a = 0; a < 3; ++a) {
        #pragma unroll
        for (int b = 0; b < 3; ++b) {
            float pav[3][5][2];
            #pragma unroll
            for (int c = 0; c < 3; ++c) {
                if (cg::allowedC(a, b, c)) {
                    #pragma unroll
                    for (int dk = 0; dk < 2 * c + 1; ++dk)
                        if (cg::rowNZ(a, b, c, dk)) { pav[c][dk][0] = 0.f; pav[c][dk][1] = 0.f; }
                }
            }
            #pragma unroll
            for (int di = 0; di < 2 * a + 1; ++di) {
                #pragma unroll
                for (int dj = 0; dj < 2 * b + 1; ++dj) {
                    const int i = a * a + di, j = b * b + dj;
                    if (cg::anyNZ(i, j)) {
                        const float p0 = xl[i]     * yl[j];
                        const float p1 = xl[9 + i] * yl[9 + j];
                        #pragma unroll
                        for (int c = 0; c < 3; ++c) {
                            if (cg::allowedC(a, b, c)) {
                                #pragma unroll
                                for (int dk = 0; dk < 2 * c + 1; ++dk) {
                                    const float kv = cg::KT.v[i][j][c * c + dk];
                                    if (kv != 0.0f) {
                                        pav[c][dk][0] += kv * p0;
                                        pav[c][dk][1] += kv * p1;
                                    }
                                }
                            }
                        }
                    }
                }
            }
            #pragma unroll
            for (int c = 0; c < 3; ++c) {
                if (cg::allowedC(a, b, c)) {
                    const int p = cg::pathOf(a, b, c);
                    #pragma unroll
                    for (int dk = 0; dk < 2 * c + 1; ++dk) {
                        if (cg::rowNZ(a, b, c, dk)) {
                            acc[c * c + dk]     += w[p] * pav[c][dk][0];
                            acc[9 + c * c + dk] += w[p] * pav[c][dk][1];
                        }
                    }
                }
            }
        }
    }

    // ---- LDS-staged coalesced store (reuse tx; same-wave DS ops are ordered) ----
    #pragma unroll
    for (int i = 0; i < 18; ++i) tx[base + i] = acc[i];
    __syncthreads();   // wave-local: ensure LDS writes visible to permuted reads

    float4* og = reinterpret_cast<float4*>(out) + blk * (long)TILE4;
    const float4* t4 = reinterpret_cast<const float4*>(tx);
    #pragma unroll
    for (int r = 0; r < 4; ++r) og[r * 64 + lane] = t4[r * 64 + lane];
    if (lane < 32) og[256 + lane] = t4[256 + lane];
}

// ===========================================================================

extern "C" void kernel_launch(void* const* d_in, const int* in_sizes, int n_in,
                              void* d_out, int out_size, void* d_ws, size_t ws_size,
                              hipStream_t stream) {
    const float* x   = (const float*)d_in[0];
    const float* y   = (const float*)d_in[1];
    const float* tpw = (const float*)d_in[2];
    const float* Wfx = (const float*)d_in[3];
    const float* bfx = (const float*)d_in[4];
    const float* Wfy = (const float*)d_in[5];
    const float* bfy = (const float*)d_in[6];
    float* out = (float*)d_out;

    long n_items = (long)out_size / 9;              // 16,777,216 (divisible by 128)
    long grid = (n_items + IPB - 1) / IPB;          // 131,072 blocks

    hipLaunchKernelGGL(tp_main_kernel, dim3((unsigned)grid), dim3(BLK), 0, stream,
                       x, y, out, tpw, Wfx, bfx, Wfy, bfy);
}

// Round 5
// 1487.456 us; speedup vs baseline: 2.4754x; 2.4754x over previous
//
#include <hip/hip_runtime.h>

// ===========================================================================
// Compile-time construction of the e3nn real Wigner-3j path tensor.
// (numerically validated in rounds 3/4: absmax 0.031 vs threshold 0.259)
// ===========================================================================
namespace cg {

constexpr double csqrt(double x) {
    double g = x < 1.0 ? 1.0 : x;
    for (int i = 0; i < 64; ++i) g = 0.5 * (g + x / g);
    return g;
}
constexpr double fact(int n) { double r = 1.0; for (int i = 2; i <= n; ++i) r *= (double)i; return r; }

constexpr double su2cg(int j1, int j2, int j3, int m1, int m2, int m3) {
    if (m1 + m2 != m3) return 0.0;
    double pre = csqrt((2.0*j3+1.0)*fact(j3+j1-j2)*fact(j3-j1+j2)*fact(j1+j2-j3)
                       *fact(j3+m3)*fact(j3-m3)
                       /(fact(j1+j2+j3+1)*fact(j1-m1)*fact(j1+m1)*fact(j2-m2)*fact(j2+m2)));
    double S = 0.0;
    for (int v = 0; v <= j1 + j2 + j3; ++v) {
        int b1 = j3-j1+j2-v, b2 = j3+m3-v, b3 = v+j1-j2-m3, b4 = j2+j3+m1-v, b5 = j1-m1+v;
        if (b1 < 0 || b2 < 0 || b3 < 0 || b4 < 0 || b5 < 0) continue;
        double term = fact(b4)*fact(b5)/(fact(v)*fact(b1)*fact(b2)*fact(b3));
        S += ((v + j2 + m2) & 1) ? -term : term;
    }
    return pre * S;
}

struct CD { double re, im; };
constexpr CD cmul(CD a, CD b) { return { a.re*b.re - a.im*b.im, a.re*b.im + a.im*b.re }; }

constexpr CD qent(int l, int r, int c) {
    const double s = 0.70710678118654752440;
    CD v{0.0, 0.0};
    int m = r - l;
    if (m < 0)       { if (c == l - m) v = { s, 0.0 }; else if (c == l + m) v = { 0.0, -s }; }
    else if (m == 0) { if (c == l)     v = { 1.0, 0.0 }; }
    else             { double sg = (m & 1) ? -1.0 : 1.0;
                       if (c == l + m) v = { sg*s, 0.0 }; else if (c == l - m) v = { 0.0, sg*s }; }
    if      (l == 1) v = { v.im, -v.re };
    else if (l == 2) v = { -v.re, -v.im };
    return v;
}

constexpr int PA_[11] = {0,0,0,1,1,1,1,2,2,2,2};
constexpr int PB_[11] = {0,1,2,0,1,1,2,0,1,2,2};
constexpr int PC_[11] = {0,1,2,1,0,2,1,2,1,0,2};
constexpr double FAN_[3] = {3.0, 4.0, 4.0};

struct KTab { float v[9][9][9]; };

constexpr KTab buildK() {
    KTab T{};
    for (int p = 0; p < 11; ++p) {
        const int a = PA_[p], b = PB_[p], c = PC_[p];
        double cgt[5][5] = {};
        for (int i = 0; i < 2*a+1; ++i)
            for (int k = 0; k < 2*b+1; ++k) {
                int m3 = (i-a) + (k-b);
                cgt[i][k] = (m3 >= -c && m3 <= c) ? su2cg(a,b,c,i-a,k-b,m3) : 0.0;
            }
        double R[5][5][5] = {};
        double nrm = 0.0;
        for (int j = 0; j < 2*a+1; ++j)
            for (int l = 0; l < 2*b+1; ++l)
                for (int m = 0; m < 2*c+1; ++m) {
                    double re = 0.0;
                    for (int i = 0; i < 2*a+1; ++i)
                        for (int k = 0; k < 2*b+1; ++k) {
                            double g = cgt[i][k];
                            if (g == 0.0) continue;
                            int n = (i-a) + (k-b) + c;
                            CD t12 = cmul(qent(a,i,j), qent(b,k,l));
                            CD q3  = qent(c,n,m);
                            re += (t12.re*q3.re + t12.im*q3.im) * g;
                        }
                    R[j][l][m] = re;
                    nrm += re*re;
                }
        double sc = csqrt((2.0*c+1.0)/FAN_[c]) / csqrt(nrm);
        for (int j = 0; j < 2*a+1; ++j)
            for (int l = 0; l < 2*b+1; ++l)
                for (int m = 0; m < 2*c+1; ++m)
                    T.v[a*a+j][b*b+l][c*c+m] = (float)(R[j][l][m] * sc);
    }
    return T;
}

constexpr KTab KT = buildK();

constexpr int pathOf(int a, int b, int c) {
    for (int p = 0; p < 11; ++p) if (PA_[p]==a && PB_[p]==b && PC_[p]==c) return p;
    return 0;
}
constexpr bool allowedC(int a, int b, int c) {
    int lo = a > b ? a - b : b - a;
    return c >= lo && c <= a + b && (((a + b + c) & 1) == 0);
}
constexpr bool anyNZ(int i, int j) {
    for (int k = 0; k < 9; ++k) if (KT.v[i][j][k] != 0.0f) return true;
    return false;
}
constexpr bool rowNZ(int a, int b, int c, int dk) {
    for (int di = 0; di < 2*a+1; ++di)
        for (int dj = 0; dj < 2*b+1; ++dj)
            if (KT.v[a*a+di][b*b+dj][c*c+dk] != 0.0f) return true;
    return false;
}

} // namespace cg

// ===========================================================================
// Main kernel: barrier-free streaming. 256 threads, TPV=2 items/thread.
// Direct strided float2 loads/stores (R1's proven-best access pattern),
// compile-time K (no C reads at all), per-wave redundant weight staging
// (identical-value LDS writes, no __syncthreads, no vmcnt(0) drain).
// ===========================================================================

#define BLK 256
#define TPV 2

__global__ __launch_bounds__(BLK) void tp_main_kernel(
        const float* __restrict__ x, const float* __restrict__ y,
        float* __restrict__ out, const float* __restrict__ tpw,
        const float* __restrict__ Wfx, const float* __restrict__ bfx,
        const float* __restrict__ Wfy, const float* __restrict__ bfy,
        long n_sets)
{
    __shared__ __align__(16) float Wc[9][24];  // [k][0..8]=Wfx row, [k][12..20]=Wfy row
    __shared__ float bs[9];

    const int t = threadIdx.x;
    const int lane = t & 63;
    const long set = (long)blockIdx.x * BLK + t;
    const bool active = set < n_sets;

    // ---- issue the 18 x/y loads FIRST (latency overlaps staging below) ----
    const float2* x2 = reinterpret_cast<const float2*>(x) + set * 9;
    const float2* y2 = reinterpret_cast<const float2*>(y) + set * 9;
    float xl[18], yl[18];   // flat: [0..8]=item0 comps, [9..17]=item1 comps
    if (active) {
        #pragma unroll
        for (int q = 0; q < 9; ++q) {
            float2 a2 = x2[q]; xl[2*q] = a2.x; xl[2*q+1] = a2.y;
            float2 b2 = y2[q]; yl[2*q] = b2.x; yl[2*q+1] = b2.y;
        }
    }

    // ---- per-wave redundant weight staging: no cross-wave barrier needed.
    //      All waves write identical values; within-wave SIMD order makes
    //      writes visible to this wave's later reads (compiler adds lgkmcnt).
    #pragma unroll
    for (int u0 = 0; u0 < 2; ++u0) {
        int u = u0 * 64 + lane;
        if (u < 81) { Wc[u / 9][u % 9] = Wfx[u]; Wc[u / 9][12 + u % 9] = Wfy[u]; }
    }
    if (lane < 9) bs[lane] = bfx[lane] + bfy[lane];

    float w[11];
    #pragma unroll
    for (int p = 0; p < 11; ++p) {
        union { float f; int i; } u;
        u.f = tpw[p];
        u.i = __builtin_amdgcn_readfirstlane(u.i);
        w[p] = u.f;
    }

    if (!active) return;

    // ---- biases ----
    float acc[18];
    #pragma unroll
    for (int k = 0; k < 9; ++k) { float bb = bs[k]; acc[k] = bb; acc[9 + k] = bb; }

    // ---- linear branches ----
    #pragma unroll
    for (int k = 0; k < 9; ++k) {
        float4 wxa = *reinterpret_cast<const float4*>(&Wc[k][0]);
        float4 wxb = *reinterpret_cast<const float4*>(&Wc[k][4]);
        float  wx8 = Wc[k][8];
        float4 wya = *reinterpret_cast<const float4*>(&Wc[k][12]);
        float4 wyb = *reinterpret_cast<const float4*>(&Wc[k][16]);
        float  wy8 = Wc[k][20];
        const float wxr[9] = {wxa.x,wxa.y,wxa.z,wxa.w,wxb.x,wxb.y,wxb.z,wxb.w,wx8};
        const float wyr[9] = {wya.x,wya.y,wya.z,wya.w,wyb.x,wyb.y,wyb.z,wyb.w,wy8};
        float s0 = acc[k], s1 = acc[9 + k];
        #pragma unroll
        for (int i = 0; i < 9; ++i) {
            s0 += wxr[i] * xl[i]     + wyr[i] * yl[i];
            s1 += wxr[i] * xl[9 + i] + wyr[i] * yl[9 + i];
        }
        acc[k] = s0; acc[9 + k] = s1;
    }

    // ---- tensor product: compile-time-folded sparse 3j constants ----
    #pragma unroll
    for (int a = 0; a < 3; ++a) {
        #pragma unroll
        for (int b = 0; b < 3; ++b) {
            float pav[3][5][2];
            #pragma unroll
            for (int c = 0; c < 3; ++c) {
                if (cg::allowedC(a, b, c)) {
                    #pragma unroll
                    for (int dk = 0; dk < 2 * c + 1; ++dk)
                        if (cg::rowNZ(a, b, c, dk)) { pav[c][dk][0] = 0.f; pav[c][dk][1] = 0.f; }
                }
            }
            #pragma unroll
            for (int di = 0; di < 2 * a + 1; ++di) {
                #pragma unroll
                for (int dj = 0; dj < 2 * b + 1; ++dj) {
                    const int i = a * a + di, j = b * b + dj;
                    if (cg::anyNZ(i, j)) {
                        const float p0 = xl[i]     * yl[j];
                        const float p1 = xl[9 + i] * yl[9 + j];
                        #pragma unroll
                        for (int c = 0; c < 3; ++c) {
                            if (cg::allowedC(a, b, c)) {
                                #pragma unroll
                                for (int dk = 0; dk < 2 * c + 1; ++dk) {
                                    const float kv = cg::KT.v[i][j][c * c + dk];
                                    if (kv != 0.0f) {
                                        pav[c][dk][0] += kv * p0;
                                        pav[c][dk][1] += kv * p1;
                                    }
                                }
                            }
                        }
                    }
                }
            }
            #pragma unroll
            for (int c = 0; c < 3; ++c) {
                if (cg::allowedC(a, b, c)) {
                    const int p = cg::pathOf(a, b, c);
                    #pragma unroll
                    for (int dk = 0; dk < 2 * c + 1; ++dk) {
                        if (cg::rowNZ(a, b, c, dk)) {
                            acc[c * c + dk]     += w[p] * pav[c][dk][0];
                            acc[9 + c * c + dk] += w[p] * pav[c][dk][1];
                        }
                    }
                }
            }
        }
    }

    // ---- direct strided store ----
    float2* o2 = reinterpret_cast<float2*>(out) + set * 9;
    #pragma unroll
    for (int q = 0; q < 9; ++q)
        o2[q] = make_float2(acc[2 * q], acc[2 * q + 1]);
}

// ===========================================================================

extern "C" void kernel_launch(void* const* d_in, const int* in_sizes, int n_in,
                              void* d_out, int out_size, void* d_ws, size_t ws_size,
                              hipStream_t stream) {
    const float* x   = (const float*)d_in[0];
    const float* y   = (const float*)d_in[1];
    const float* tpw = (const float*)d_in[2];
    const float* Wfx = (const float*)d_in[3];
    const float* bfx = (const float*)d_in[4];
    const float* Wfy = (const float*)d_in[5];
    const float* bfy = (const float*)d_in[6];
    float* out = (float*)d_out;

    long n_items = (long)out_size / 9;              // 16,777,216
    long n_sets = (n_items + TPV - 1) / TPV;        // 8,388,608
    long grid = (n_sets + BLK - 1) / BLK;           // 32,768

    hipLaunchKernelGGL(tp_main_kernel, dim3((unsigned)grid), dim3(BLK), 0, stream,
                       x, y, out, tpw, Wfx, bfx, Wfy, bfy, n_sets);
}